// Round 14
// baseline (209.363 us; speedup 1.0000x reference)
//
#include <hip/hip_runtime.h>
#include <hip/hip_bf16.h>

// Problem constants: B=2, S=2048, D=1024, H=16, A=64
#define B_ 2
#define S_ 2048
#define D_ 1024
#define H_ 16
#define A_ 64

typedef __attribute__((ext_vector_type(8))) short bf16x8;
typedef __attribute__((ext_vector_type(4))) float f32x4;
typedef __attribute__((ext_vector_type(4))) unsigned int u32x4;
typedef __attribute__((ext_vector_type(2))) unsigned int u32x2;

#define QSCALE 0.1803368801111204f   // 1/sqrt(64) * log2(e): softmax done in exp2 domain
#define SMAX 8.0f                    // static softmax shift (exp2 domain); see flash_kernel

__device__ inline short f2bf(float f) {
    union { float f; unsigned u; } x; x.f = f;
    unsigned r = x.u + 0x7fff + ((x.u >> 16) & 1);   // RNE
    return (short)(r >> 16);
}

// async global->LDS, 16B per lane; LDS dest = wave-uniform base + lane*16 (linear)
__device__ __forceinline__ void gld16(const short* g, short* l) {
    __builtin_amdgcn_global_load_lds(
        (const __attribute__((address_space(1))) unsigned int*)g,
        (__attribute__((address_space(3))) unsigned int*)l, 16, 0, 0);
}

// ---- gfx950 register-only cross-lane helpers (VALU; no LDS pipe) ----
__device__ inline unsigned cvt_pk_bf16(float lo, float hi) {
    unsigned r;
    asm("v_cvt_pk_bf16_f32 %0, %1, %2" : "=v"(r) : "v"(lo), "v"(hi));
    return r;
}
__device__ inline void pl32swap(unsigned &a, unsigned &b) {
    u32x2 r = __builtin_amdgcn_permlane32_swap(a, b, false, false);
    a = r[0]; b = r[1];
}
__device__ inline void pl16swap(unsigned &a, unsigned &b) {
    u32x2 r = __builtin_amdgcn_permlane16_swap(a, b, false, false);
    a = r[0]; b = r[1];
}
__device__ inline float cross_quad_sum(float x) {
    unsigned a = __builtin_bit_cast(unsigned, x), b = a;
    pl32swap(a, b);
    float y = __builtin_bit_cast(float, a) + __builtin_bit_cast(float, b);
    unsigned c = __builtin_bit_cast(unsigned, y), d = c;
    pl16swap(c, d);
    return __builtin_bit_cast(float, c) + __builtin_bit_cast(float, d);
}

// ---------------- kernel 1: fp32 -> bf16 cast of residual ----------------
__global__ __launch_bounds__(256) void cast_kernel(const float* __restrict__ x,
                                                   short* __restrict__ y, int n) {
    int i = (blockIdx.x * 256 + threadIdx.x) * 8;
    if (i < n) {
        float4 a = *(const float4*)(x + i);
        float4 b = *(const float4*)(x + i + 4);
        bf16x8 o;
        o[0]=f2bf(a.x); o[1]=f2bf(a.y); o[2]=f2bf(a.z); o[3]=f2bf(a.w);
        o[4]=f2bf(b.x); o[5]=f2bf(b.y); o[6]=f2bf(b.z); o[7]=f2bf(b.w);
        *(bf16x8*)(y + i) = o;
    }
}

// ---------------- kernel 1b: transpose+cast weights to bf16 [n][k] ----------------
__global__ __launch_bounds__(256) void wtrans_kernel(
    const float* __restrict__ Wq, const float* __restrict__ Wk,
    const float* __restrict__ Wv, const float* __restrict__ Wo,
    short* __restrict__ Wt, short* __restrict__ Wot) {
    const int kt = blockIdx.x, yy = blockIdx.y, z = blockIdx.z;
    __shared__ short T[64 * 72];
    const int tid = threadIdx.x;
    const int r = tid >> 2, c0 = (tid & 3) * 16;
    const float* src;
    if (z < 3) {
        const float* W = z == 0 ? Wq : (z == 1 ? Wk : Wv);
        src = &W[yy * (D_ * A_) + (kt * 64 + r) * A_ + c0];
    } else {
        src = &Wo[(kt * 64 + r) * D_ + yy * 64 + c0];
    }
    #pragma unroll
    for (int q = 0; q < 4; q++) {
        float4 f = *(const float4*)(src + q * 4);
        T[r * 72 + c0 + q * 4 + 0] = f2bf(f.x);
        T[r * 72 + c0 + q * 4 + 1] = f2bf(f.y);
        T[r * 72 + c0 + q * 4 + 2] = f2bf(f.z);
        T[r * 72 + c0 + q * 4 + 3] = f2bf(f.w);
    }
    __syncthreads();
    const int a = tid >> 2, kc = (tid & 3) * 16;
    bf16x8 o0, o1;
    #pragma unroll
    for (int j = 0; j < 8; j++) {
        o0[j] = T[(kc + j) * 72 + a];
        o1[j] = T[(kc + 8 + j) * 72 + a];
    }
    const int n_base = (z < 3) ? z * 1024 + yy * 64 : yy * 64;
    short* dst = (z < 3) ? &Wt[(n_base + a) * D_ + kt * 64 + kc]
                         : &Wot[(n_base + a) * D_ + kt * 64 + kc];
    *(bf16x8*)dst = o0;
    *(bf16x8*)(dst + 8) = o1;
}

// ---------------- kernel 2: QKV as one GEMM [4096 x 3072 x 1024] (R2/R8 reg-staged) -------
__global__ __launch_bounds__(256) void qkv_gemm(
    const short* __restrict__ X, const short* __restrict__ Wt,
    const float* __restrict__ bq, const float* __restrict__ bk, const float* __restrict__ bv,
    short* __restrict__ Qb, short* __restrict__ Kb, short* __restrict__ Vt) {
    const int mt = blockIdx.x, nt = blockIdx.y;
    const int m0 = mt * 128, n0 = nt * 128;
    const int sel = n0 >> 10;
    __shared__ short Xl[2][128 * 40], Wl[2][128 * 40];
    const int tid = threadIdx.x, wv = tid >> 6, lane = tid & 63, quad = lane >> 4, l16 = lane & 15;
    const int grow = tid >> 1, gk = (tid & 1) * 16;
    f32x4 acc[4][4] = {};
    bf16x8 xr0, xr1, wr0, wr1;
    {
        const short* xs = &X[(m0 + grow) * D_ + gk];
        xr0 = *(const bf16x8*)xs; xr1 = *(const bf16x8*)(xs + 8);
        const short* wsp = &Wt[(n0 + grow) * D_ + gk];
        wr0 = *(const bf16x8*)wsp; wr1 = *(const bf16x8*)(wsp + 8);
    }
    const int rm = (wv & 1) * 64, cn = (wv >> 1) * 64;
    for (int i = 0; i < 32; i++) {
        const int bu = i & 1;
        *(bf16x8*)&Xl[bu][grow * 40 + gk]     = xr0;
        *(bf16x8*)&Xl[bu][grow * 40 + gk + 8] = xr1;
        *(bf16x8*)&Wl[bu][grow * 40 + gk]     = wr0;
        *(bf16x8*)&Wl[bu][grow * 40 + gk + 8] = wr1;
        __syncthreads();
        if (i < 31) {
            const int k0 = (i + 1) * 32;
            const short* xs = &X[(m0 + grow) * D_ + k0 + gk];
            xr0 = *(const bf16x8*)xs; xr1 = *(const bf16x8*)(xs + 8);
            const short* wsp = &Wt[(n0 + grow) * D_ + k0 + gk];
            wr0 = *(const bf16x8*)wsp; wr1 = *(const bf16x8*)(wsp + 8);
        }
        bf16x8 af[4];
        #pragma unroll
        for (int rt = 0; rt < 4; rt++)
            af[rt] = *(bf16x8*)&Xl[bu][(rm + rt * 16 + l16) * 40 + quad * 8];
        #pragma unroll
        for (int ct = 0; ct < 4; ct++) {
            bf16x8 bf = *(bf16x8*)&Wl[bu][(cn + ct * 16 + l16) * 40 + quad * 8];
            #pragma unroll
            for (int rt = 0; rt < 4; rt++)
                acc[rt][ct] = __builtin_amdgcn_mfma_f32_16x16x32_bf16(af[rt], bf, acc[rt][ct], 0, 0, 0);
        }
    }
    const int b = m0 >> 11;
    const float* bias = sel == 0 ? bq : (sel == 1 ? bk : bv);
    if (sel < 2) {
        short* dst = sel == 0 ? Qb : Kb;
        const float scale = sel == 0 ? QSCALE : 1.0f;
        #pragma unroll
        for (int ct = 0; ct < 4; ct++) {
            const int n = n0 + cn + ct * 16 + l16;
            const int h = (n >> 6) & 15, a = n & 63;
            const float bi = bias[n & 1023];
            #pragma unroll
            for (int rt = 0; rt < 4; rt++)
                #pragma unroll
                for (int r = 0; r < 4; r++) {
                    const int row = m0 + rm + rt * 16 + quad * 4 + r;
                    const int s = row & (S_ - 1);
                    dst[(((b * H_) + h) * S_ + s) * A_ + a] = f2bf((acc[rt][ct][r] + bi) * scale);
                }
        }
    } else {
        #pragma unroll
        for (int ct = 0; ct < 4; ct++) {
            const int n = n0 + cn + ct * 16 + l16;
            const int h = (n >> 6) & 15, a = n & 63;
            const float bi = bias[n & 1023];
            #pragma unroll
            for (int rt = 0; rt < 4; rt++) {
                short4 pk;
                pk.x = f2bf(acc[rt][ct][0] + bi);
                pk.y = f2bf(acc[rt][ct][1] + bi);
                pk.z = f2bf(acc[rt][ct][2] + bi);
                pk.w = f2bf(acc[rt][ct][3] + bi);
                const int row = m0 + rm + rt * 16 + quad * 4;
                const int s = row & (S_ - 1);
                *(short4*)&Vt[(((b * H_) + h) * A_ + a) * S_ + s] = pk;
            }
        }
    }
}

// ---------------- kernel 3: flash attention — static-max + gld_lds K/V staging (R14) ------
// R14 change vs R13 (single lever): K/V staging via global_load_lds. Structural drop-in:
// 512 threads x 16B = exactly one 8KB tile per issue; LDS dest Kl[tid*16B] is already
// linear (gld_lds's required pattern); global source keeps the per-lane srow/scol map.
// Deletes per thread/round: 2 load->reg + 2 ds_write_b128 + ~8 VGPRs. Barrier algebra:
// one __syncthreads per round; pre-barrier lgkm drain protects buf[bu] reads before the
// post-barrier gld overwrites it; pre-barrier vmcnt drain completes buf[bu^1] fills.
__global__ __launch_bounds__(512, 4) void flash_kernel(
    const short* __restrict__ Qb, const short* __restrict__ Kb,
    const short* __restrict__ Vt, short* __restrict__ Z) {
    const int xx = blockIdx.x, h = blockIdx.y, b = blockIdx.z;
    const int x = (((h >> 3) ^ b) & 1) ? (15 - xx) : xx;
    const int bh = b * H_ + h;
    const int qa = 2 * x, qb = 2 * x + 1;   // adjacent q-tiles; qmax = qb
    __shared__ short Kl[2][4096], Vl[2][4096];
    const int tid = threadIdx.x, wv = tid >> 6, lane = tid & 63, quad = lane >> 4, l16 = lane & 15;
    const int wg = wv & 3;
    const int myqt = (wv < 4) ? qb : qa;
    const int qpos = wg * 16 + l16;

    const int L = tid;
    const int srow = (L >> 7) * 16 + (L & 15);
    const int scol = ((L >> 6) & 1) * 32 + ((L >> 4) & 3) * 8;

    const short* qptr = &Qb[(bh * S_ + myqt * 64 + wg * 16 + l16) * A_ + quad * 8];
    bf16x8 qf[2] = { *(const bf16x8*)qptr, *(const bf16x8*)(qptr + 32) };

    f32x4 O[4] = {};
    float l_i = 0.f;                       // in-lane partial row-sum (cross-quad at end)

    const short* kgp = &Kb[(bh * S_ + srow) * A_ + scol];   // + kt*64*A per tile
    const short* vgp = &Vt[(bh * A_ + srow) * S_ + scol];   // + kt*64 per tile

    gld16(kgp, &Kl[0][L * 8]);
    gld16(vgp, &Vl[0][L * 8]);

    for (int kt = 0; kt <= qb; kt++) {
        const int bu = kt & 1;
        __syncthreads();                   // buf[bu] fills drained; prior reads of buf[bu^1] done
        if (kt < qb) {
            gld16(kgp + (kt + 1) * 64 * A_, &Kl[bu ^ 1][L * 8]);
            gld16(vgp + (kt + 1) * 64,      &Vl[bu ^ 1][L * 8]);
        }
        if (kt <= myqt) {
            f32x4 sacc[4] = {};
            #pragma unroll
            for (int kk = 0; kk < 2; kk++)
                #pragma unroll
                for (int ct = 0; ct < 4; ct++) {
                    bf16x8 kf = *(bf16x8*)&Kl[bu][((ct * 2 + kk) * 64 + lane) * 8];
                    sacc[ct] = __builtin_amdgcn_mfma_f32_16x16x32_bf16(kf, qf[kk], sacc[ct], 0, 0, 0);
                }
            if (kt == myqt) {
                #pragma unroll
                for (int ct = 0; ct < 4; ct++)
                    #pragma unroll
                    for (int r = 0; r < 4; r++)
                        if (ct * 16 + quad * 4 + r > qpos) sacc[ct][r] = -1e30f;
            }
            // static-shift softmax numerator: p = exp2(s - SMAX); masked -> 0
            #pragma unroll
            for (int ct = 0; ct < 4; ct++)
                #pragma unroll
                for (int r = 0; r < 4; r++)
                    sacc[ct][r] = exp2f(sacc[ct][r] - SMAX);
            f32x4 ps;
            #pragma unroll
            for (int r = 0; r < 4; r++)
                ps[r] = (sacc[0][r] + sacc[1][r]) + (sacc[2][r] + sacc[3][r]);
            l_i += (ps[0] + ps[1]) + (ps[2] + ps[3]);
            #pragma unroll
            for (int kk = 0; kk < 2; kk++) {
                unsigned A0 = cvt_pk_bf16(sacc[2 * kk][0], sacc[2 * kk][1]);
                unsigned A1 = cvt_pk_bf16(sacc[2 * kk][2], sacc[2 * kk][3]);
                unsigned B0 = cvt_pk_bf16(sacc[2 * kk + 1][0], sacc[2 * kk + 1][1]);
                unsigned B1 = cvt_pk_bf16(sacc[2 * kk + 1][2], sacc[2 * kk + 1][3]);
                pl32swap(A0, B0);
                pl16swap(A0, B0);
                pl32swap(A1, B1);
                pl16swap(A1, B1);
                u32x4 wu; wu[0] = A0; wu[1] = A1; wu[2] = B0; wu[3] = B1;
                bf16x8 pb = __builtin_bit_cast(bf16x8, wu);
                #pragma unroll
                for (int ct = 0; ct < 4; ct++) {
                    bf16x8 vf = *(bf16x8*)&Vl[bu][((ct * 2 + kk) * 64 + lane) * 8];
                    O[ct] = __builtin_amdgcn_mfma_f32_16x16x32_bf16(vf, pb, O[ct], 0, 0, 0);
                }
            }
        }
    }
    const float inv = 1.0f / cross_quad_sum(l_i);
    const int s = myqt * 64 + wg * 16 + l16;
    #pragma unroll
    for (int ct = 0; ct < 4; ct++) {
        short4 o4;
        o4.x = f2bf(O[ct][0] * inv);
        o4.y = f2bf(O[ct][1] * inv);
        o4.z = f2bf(O[ct][2] * inv);
        o4.w = f2bf(O[ct][3] * inv);
        *(short4*)&Z[(b * S_ + s) * (H_ * A_) + h * A_ + ct * 16 + quad * 4] = o4;
    }
}

// ---------------- kernel 4: output projection GEMM [4096 x 1024 x 1024] (R2/R8 reg-staged) -
__global__ __launch_bounds__(256) void proj_gemm(
    const short* __restrict__ Zb, const short* __restrict__ Wot,
    const float* __restrict__ bo, float* __restrict__ out) {
    const int mt = blockIdx.x, nt = blockIdx.y;
    const int m0 = mt * 128, n0 = nt * 64;
    __shared__ short Xl[2][128 * 40], Wl[2][64 * 40];
    const int tid = threadIdx.x, wv = tid >> 6, lane = tid & 63, quad = lane >> 4, l16 = lane & 15;
    const int grow = tid >> 1, gk = (tid & 1) * 16;
    const bool doW = (tid < 128);          // W tile 64x32 = 2048 shorts = 128 thr x 16
    f32x4 acc[4][2] = {};
    bf16x8 xr0, xr1, wr0, wr1;
    {
        const short* xs = &Zb[(m0 + grow) * D_ + gk];
        xr0 = *(const bf16x8*)xs; xr1 = *(const bf16x8*)(xs + 8);
        if (doW) {
            const short* wsp = &Wot[(n0 + grow) * D_ + gk];
            wr0 = *(const bf16x8*)wsp; wr1 = *(const bf16x8*)(wsp + 8);
        }
    }
    const int rm = (wv & 1) * 64, cn = (wv >> 1) * 32;
    for (int i = 0; i < 32; i++) {
        const int bu = i & 1;
        *(bf16x8*)&Xl[bu][grow * 40 + gk]     = xr0;
        *(bf16x8*)&Xl[bu][grow * 40 + gk + 8] = xr1;
        if (doW) {
            *(bf16x8*)&Wl[bu][grow * 40 + gk]     = wr0;
            *(bf16x8*)&Wl[bu][grow * 40 + gk + 8] = wr1;
        }
        __syncthreads();
        if (i < 31) {
            const int k0 = (i + 1) * 32;
            const short* xs = &Zb[(m0 + grow) * D_ + k0 + gk];
            xr0 = *(const bf16x8*)xs; xr1 = *(const bf16x8*)(xs + 8);
            if (doW) {
                const short* wsp = &Wot[(n0 + grow) * D_ + k0 + gk];
                wr0 = *(const bf16x8*)wsp; wr1 = *(const bf16x8*)(wsp + 8);
            }
        }
        bf16x8 af[4];
        #pragma unroll
        for (int rt = 0; rt < 4; rt++)
            af[rt] = *(bf16x8*)&Xl[bu][(rm + rt * 16 + l16) * 40 + quad * 8];
        #pragma unroll
        for (int ct = 0; ct < 2; ct++) {
            bf16x8 bf = *(bf16x8*)&Wl[bu][(cn + ct * 16 + l16) * 40 + quad * 8];
            #pragma unroll
            for (int rt = 0; rt < 4; rt++)
                acc[rt][ct] = __builtin_amdgcn_mfma_f32_16x16x32_bf16(af[rt], bf, acc[rt][ct], 0, 0, 0);
        }
    }
    #pragma unroll
    for (int ct = 0; ct < 2; ct++) {
        const int n = n0 + cn + ct * 16 + l16;
        const float bi = bo[n];
        #pragma unroll
        for (int rt = 0; rt < 4; rt++)
            #pragma unroll
            for (int r = 0; r < 4; r++) {
                const int row = m0 + rm + rt * 16 + quad * 4 + r;
                out[row * D_ + n] = acc[rt][ct][r] + bi;
            }
    }
}

extern "C" void kernel_launch(void* const* d_in, const int* in_sizes, int n_in,
                              void* d_out, int out_size, void* d_ws, size_t ws_size,
                              hipStream_t stream) {
    const float* residual = (const float*)d_in[0];
    const float* Wq = (const float*)d_in[1];
    const float* Wk = (const float*)d_in[2];
    const float* Wv = (const float*)d_in[3];
    const float* Wo = (const float*)d_in[4];
    const float* bq = (const float*)d_in[5];
    const float* bk = (const float*)d_in[6];
    const float* bv = (const float*)d_in[7];
    const float* bo = (const float*)d_in[8];
    float* out = (float*)d_out;

    char* ws = (char*)d_ws;
    const size_t NE = (size_t)B_ * S_ * D_;           // 4,194,304
    short* Xbf = (short*)(ws);                        //  8 MB  [B*S, D] bf16
    short* Wt  = (short*)(ws +  8ull * 1024 * 1024);  //  6 MB  [3072, 1024] bf16 (qkv, transposed)
    short* Wot = (short*)(ws + 14ull * 1024 * 1024);  //  2 MB  [1024, 1024] bf16 (Wo, transposed)
    short* Qb  = (short*)(ws + 16ull * 1024 * 1024);  //  8 MB  [B,H,S,A]
    short* Kb  = (short*)(ws + 24ull * 1024 * 1024);  //  8 MB  [B,H,S,A]
    short* Vt  = (short*)(ws + 32ull * 1024 * 1024);  //  8 MB  [B,H,A,S]
    short* Zb  = (short*)(ws + 40ull * 1024 * 1024);  //  8 MB  [B,S,H*A]

    hipLaunchKernelGGL(cast_kernel, dim3((int)(NE / (256 * 8))), dim3(256), 0, stream,
                       residual, Xbf, (int)NE);
    hipLaunchKernelGGL(wtrans_kernel, dim3(16, 16, 4), dim3(256), 0, stream,
                       Wq, Wk, Wv, Wo, Wt, Wot);
    hipLaunchKernelGGL(qkv_gemm, dim3(32, 24), dim3(256), 0, stream,
                       Xbf, Wt, bq, bk, bv, Qb, Kb, Vt);
    hipLaunchKernelGGL(flash_kernel, dim3(16, H_, B_), dim3(512), 0, stream,
                       Qb, Kb, Vt, Zb);
    hipLaunchKernelGGL(proj_gemm, dim3(32, 16), dim3(256), 0, stream,
                       Zb, Wot, bo, out);
}

// Round 15
// 194.876 us; speedup vs baseline: 1.0743x; 1.0743x over previous
//
#include <hip/hip_runtime.h>
#include <hip/hip_bf16.h>

// Problem constants: B=2, S=2048, D=1024, H=16, A=64
#define B_ 2
#define S_ 2048
#define D_ 1024
#define H_ 16
#define A_ 64

typedef __attribute__((ext_vector_type(8))) short bf16x8;
typedef __attribute__((ext_vector_type(4))) float f32x4;
typedef __attribute__((ext_vector_type(4))) unsigned int u32x4;
typedef __attribute__((ext_vector_type(2))) unsigned int u32x2;

#define QSCALE 0.1803368801111204f   // 1/sqrt(64) * log2(e): softmax done in exp2 domain
#define SMAX 8.0f                    // static softmax shift (exp2 domain); see flash_kernel

__device__ inline short f2bf(float f) {
    union { float f; unsigned u; } x; x.f = f;
    unsigned r = x.u + 0x7fff + ((x.u >> 16) & 1);   // RNE
    return (short)(r >> 16);
}

// ---- gfx950 register-only cross-lane helpers (VALU; no LDS pipe) ----
__device__ inline unsigned cvt_pk_bf16(float lo, float hi) {
    unsigned r;
    asm("v_cvt_pk_bf16_f32 %0, %1, %2" : "=v"(r) : "v"(lo), "v"(hi));
    return r;
}
__device__ inline void pl32swap(unsigned &a, unsigned &b) {
    u32x2 r = __builtin_amdgcn_permlane32_swap(a, b, false, false);
    a = r[0]; b = r[1];
}
__device__ inline void pl16swap(unsigned &a, unsigned &b) {
    u32x2 r = __builtin_amdgcn_permlane16_swap(a, b, false, false);
    a = r[0]; b = r[1];
}
__device__ inline float cross_quad_sum(float x) {
    unsigned a = __builtin_bit_cast(unsigned, x), b = a;
    pl32swap(a, b);
    float y = __builtin_bit_cast(float, a) + __builtin_bit_cast(float, b);
    unsigned c = __builtin_bit_cast(unsigned, y), d = c;
    pl16swap(c, d);
    return __builtin_bit_cast(float, c) + __builtin_bit_cast(float, d);
}

// ---------------- kernel 1: fp32 -> bf16 cast of residual ----------------
__global__ __launch_bounds__(256) void cast_kernel(const float* __restrict__ x,
                                                   short* __restrict__ y, int n) {
    int i = (blockIdx.x * 256 + threadIdx.x) * 8;
    if (i < n) {
        float4 a = *(const float4*)(x + i);
        float4 b = *(const float4*)(x + i + 4);
        bf16x8 o;
        o[0]=f2bf(a.x); o[1]=f2bf(a.y); o[2]=f2bf(a.z); o[3]=f2bf(a.w);
        o[4]=f2bf(b.x); o[5]=f2bf(b.y); o[6]=f2bf(b.z); o[7]=f2bf(b.w);
        *(bf16x8*)(y + i) = o;
    }
}

// ---------------- kernel 1b: transpose+cast weights to bf16 [n][k] ----------------
__global__ __launch_bounds__(256) void wtrans_kernel(
    const float* __restrict__ Wq, const float* __restrict__ Wk,
    const float* __restrict__ Wv, const float* __restrict__ Wo,
    short* __restrict__ Wt, short* __restrict__ Wot) {
    const int kt = blockIdx.x, yy = blockIdx.y, z = blockIdx.z;
    __shared__ short T[64 * 72];
    const int tid = threadIdx.x;
    const int r = tid >> 2, c0 = (tid & 3) * 16;
    const float* src;
    if (z < 3) {
        const float* W = z == 0 ? Wq : (z == 1 ? Wk : Wv);
        src = &W[yy * (D_ * A_) + (kt * 64 + r) * A_ + c0];
    } else {
        src = &Wo[(kt * 64 + r) * D_ + yy * 64 + c0];
    }
    #pragma unroll
    for (int q = 0; q < 4; q++) {
        float4 f = *(const float4*)(src + q * 4);
        T[r * 72 + c0 + q * 4 + 0] = f2bf(f.x);
        T[r * 72 + c0 + q * 4 + 1] = f2bf(f.y);
        T[r * 72 + c0 + q * 4 + 2] = f2bf(f.z);
        T[r * 72 + c0 + q * 4 + 3] = f2bf(f.w);
    }
    __syncthreads();
    const int a = tid >> 2, kc = (tid & 3) * 16;
    bf16x8 o0, o1;
    #pragma unroll
    for (int j = 0; j < 8; j++) {
        o0[j] = T[(kc + j) * 72 + a];
        o1[j] = T[(kc + 8 + j) * 72 + a];
    }
    const int n_base = (z < 3) ? z * 1024 + yy * 64 : yy * 64;
    short* dst = (z < 3) ? &Wt[(n_base + a) * D_ + kt * 64 + kc]
                         : &Wot[(n_base + a) * D_ + kt * 64 + kc];
    *(bf16x8*)dst = o0;
    *(bf16x8*)(dst + 8) = o1;
}

// ---------------- kernel 2: QKV as one GEMM [4096 x 3072 x 1024] (R2/R8 reg-staged) -------
__global__ __launch_bounds__(256) void qkv_gemm(
    const short* __restrict__ X, const short* __restrict__ Wt,
    const float* __restrict__ bq, const float* __restrict__ bk, const float* __restrict__ bv,
    short* __restrict__ Qb, short* __restrict__ Kb, short* __restrict__ Vt) {
    const int mt = blockIdx.x, nt = blockIdx.y;
    const int m0 = mt * 128, n0 = nt * 128;
    const int sel = n0 >> 10;
    __shared__ short Xl[2][128 * 40], Wl[2][128 * 40];
    const int tid = threadIdx.x, wv = tid >> 6, lane = tid & 63, quad = lane >> 4, l16 = lane & 15;
    const int grow = tid >> 1, gk = (tid & 1) * 16;
    f32x4 acc[4][4] = {};
    bf16x8 xr0, xr1, wr0, wr1;
    {
        const short* xs = &X[(m0 + grow) * D_ + gk];
        xr0 = *(const bf16x8*)xs; xr1 = *(const bf16x8*)(xs + 8);
        const short* wsp = &Wt[(n0 + grow) * D_ + gk];
        wr0 = *(const bf16x8*)wsp; wr1 = *(const bf16x8*)(wsp + 8);
    }
    const int rm = (wv & 1) * 64, cn = (wv >> 1) * 64;
    for (int i = 0; i < 32; i++) {
        const int bu = i & 1;
        *(bf16x8*)&Xl[bu][grow * 40 + gk]     = xr0;
        *(bf16x8*)&Xl[bu][grow * 40 + gk + 8] = xr1;
        *(bf16x8*)&Wl[bu][grow * 40 + gk]     = wr0;
        *(bf16x8*)&Wl[bu][grow * 40 + gk + 8] = wr1;
        __syncthreads();
        if (i < 31) {
            const int k0 = (i + 1) * 32;
            const short* xs = &X[(m0 + grow) * D_ + k0 + gk];
            xr0 = *(const bf16x8*)xs; xr1 = *(const bf16x8*)(xs + 8);
            const short* wsp = &Wt[(n0 + grow) * D_ + k0 + gk];
            wr0 = *(const bf16x8*)wsp; wr1 = *(const bf16x8*)(wsp + 8);
        }
        bf16x8 af[4];
        #pragma unroll
        for (int rt = 0; rt < 4; rt++)
            af[rt] = *(bf16x8*)&Xl[bu][(rm + rt * 16 + l16) * 40 + quad * 8];
        #pragma unroll
        for (int ct = 0; ct < 4; ct++) {
            bf16x8 bf = *(bf16x8*)&Wl[bu][(cn + ct * 16 + l16) * 40 + quad * 8];
            #pragma unroll
            for (int rt = 0; rt < 4; rt++)
                acc[rt][ct] = __builtin_amdgcn_mfma_f32_16x16x32_bf16(af[rt], bf, acc[rt][ct], 0, 0, 0);
        }
    }
    const int b = m0 >> 11;
    const float* bias = sel == 0 ? bq : (sel == 1 ? bk : bv);
    if (sel < 2) {
        short* dst = sel == 0 ? Qb : Kb;
        const float scale = sel == 0 ? QSCALE : 1.0f;
        #pragma unroll
        for (int ct = 0; ct < 4; ct++) {
            const int n = n0 + cn + ct * 16 + l16;
            const int h = (n >> 6) & 15, a = n & 63;
            const float bi = bias[n & 1023];
            #pragma unroll
            for (int rt = 0; rt < 4; rt++)
                #pragma unroll
                for (int r = 0; r < 4; r++) {
                    const int row = m0 + rm + rt * 16 + quad * 4 + r;
                    const int s = row & (S_ - 1);
                    dst[(((b * H_) + h) * S_ + s) * A_ + a] = f2bf((acc[rt][ct][r] + bi) * scale);
                }
        }
    } else {
        #pragma unroll
        for (int ct = 0; ct < 4; ct++) {
            const int n = n0 + cn + ct * 16 + l16;
            const int h = (n >> 6) & 15, a = n & 63;
            const float bi = bias[n & 1023];
            #pragma unroll
            for (int rt = 0; rt < 4; rt++) {
                short4 pk;
                pk.x = f2bf(acc[rt][ct][0] + bi);
                pk.y = f2bf(acc[rt][ct][1] + bi);
                pk.z = f2bf(acc[rt][ct][2] + bi);
                pk.w = f2bf(acc[rt][ct][3] + bi);
                const int row = m0 + rm + rt * 16 + quad * 4;
                const int s = row & (S_ - 1);
                *(short4*)&Vt[(((b * H_) + h) * A_ + a) * S_ + s] = pk;
            }
        }
    }
}

// ---------------- kernel 3: flash attention — adjacent pairs + static-max softmax ---------
// R15 = R13 verbatim (measured session best, 195.5 us). R14's gld_lds staging reverted:
// it moved staging latency into the barrier vmcnt drain (flash 45->60 us, VALUBusy 53->34).
// Reg-staged K/V + wave-level overlap is the measured local optimum for this structure.
__global__ __launch_bounds__(512, 4) void flash_kernel(
    const short* __restrict__ Qb, const short* __restrict__ Kb,
    const short* __restrict__ Vt, short* __restrict__ Z) {
    const int xx = blockIdx.x, h = blockIdx.y, b = blockIdx.z;
    const int x = (((h >> 3) ^ b) & 1) ? (15 - xx) : xx;
    const int bh = b * H_ + h;
    const int qa = 2 * x, qb = 2 * x + 1;   // adjacent q-tiles; qmax = qb
    __shared__ short Kl[2][4096], Vl[2][4096];
    const int tid = threadIdx.x, wv = tid >> 6, lane = tid & 63, quad = lane >> 4, l16 = lane & 15;
    const int wg = wv & 3;
    const int myqt = (wv < 4) ? qb : qa;
    const int qpos = wg * 16 + l16;

    const int L = tid;
    const int srow = (L >> 7) * 16 + (L & 15);
    const int scol = ((L >> 6) & 1) * 32 + ((L >> 4) & 3) * 8;

    const short* qptr = &Qb[(bh * S_ + myqt * 64 + wg * 16 + l16) * A_ + quad * 8];
    bf16x8 qf[2] = { *(const bf16x8*)qptr, *(const bf16x8*)(qptr + 32) };

    f32x4 O[4] = {};
    float l_i = 0.f;                       // in-lane partial row-sum (cross-quad at end)

    bf16x8 kreg = *(const bf16x8*)&Kb[(bh * S_ + srow) * A_ + scol];
    bf16x8 vreg = *(const bf16x8*)&Vt[(bh * A_ + srow) * S_ + scol];

    for (int kt = 0; kt <= qb; kt++) {
        const int bu = kt & 1;
        *(bf16x8*)&Kl[bu][L * 8] = kreg;
        *(bf16x8*)&Vl[bu][L * 8] = vreg;
        __syncthreads();
        if (kt < qb) {
            kreg = *(const bf16x8*)&Kb[(bh * S_ + (kt + 1) * 64 + srow) * A_ + scol];
            vreg = *(const bf16x8*)&Vt[(bh * A_ + srow) * S_ + (kt + 1) * 64 + scol];
        }
        if (kt <= myqt) {
            f32x4 sacc[4] = {};
            #pragma unroll
            for (int kk = 0; kk < 2; kk++)
                #pragma unroll
                for (int ct = 0; ct < 4; ct++) {
                    bf16x8 kf = *(bf16x8*)&Kl[bu][((ct * 2 + kk) * 64 + lane) * 8];
                    sacc[ct] = __builtin_amdgcn_mfma_f32_16x16x32_bf16(kf, qf[kk], sacc[ct], 0, 0, 0);
                }
            if (kt == myqt) {
                #pragma unroll
                for (int ct = 0; ct < 4; ct++)
                    #pragma unroll
                    for (int r = 0; r < 4; r++)
                        if (ct * 16 + quad * 4 + r > qpos) sacc[ct][r] = -1e30f;
            }
            // static-shift softmax numerator: p = exp2(s - SMAX); masked -> 0
            #pragma unroll
            for (int ct = 0; ct < 4; ct++)
                #pragma unroll
                for (int r = 0; r < 4; r++)
                    sacc[ct][r] = exp2f(sacc[ct][r] - SMAX);
            f32x4 ps;
            #pragma unroll
            for (int r = 0; r < 4; r++)
                ps[r] = (sacc[0][r] + sacc[1][r]) + (sacc[2][r] + sacc[3][r]);
            l_i += (ps[0] + ps[1]) + (ps[2] + ps[3]);
            #pragma unroll
            for (int kk = 0; kk < 2; kk++) {
                unsigned A0 = cvt_pk_bf16(sacc[2 * kk][0], sacc[2 * kk][1]);
                unsigned A1 = cvt_pk_bf16(sacc[2 * kk][2], sacc[2 * kk][3]);
                unsigned B0 = cvt_pk_bf16(sacc[2 * kk + 1][0], sacc[2 * kk + 1][1]);
                unsigned B1 = cvt_pk_bf16(sacc[2 * kk + 1][2], sacc[2 * kk + 1][3]);
                pl32swap(A0, B0);
                pl16swap(A0, B0);
                pl32swap(A1, B1);
                pl16swap(A1, B1);
                u32x4 wu; wu[0] = A0; wu[1] = A1; wu[2] = B0; wu[3] = B1;
                bf16x8 pb = __builtin_bit_cast(bf16x8, wu);
                #pragma unroll
                for (int ct = 0; ct < 4; ct++) {
                    bf16x8 vf = *(bf16x8*)&Vl[bu][((ct * 2 + kk) * 64 + lane) * 8];
                    O[ct] = __builtin_amdgcn_mfma_f32_16x16x32_bf16(vf, pb, O[ct], 0, 0, 0);
                }
            }
        }
    }
    const float inv = 1.0f / cross_quad_sum(l_i);
    const int s = myqt * 64 + wg * 16 + l16;
    #pragma unroll
    for (int ct = 0; ct < 4; ct++) {
        short4 o4;
        o4.x = f2bf(O[ct][0] * inv);
        o4.y = f2bf(O[ct][1] * inv);
        o4.z = f2bf(O[ct][2] * inv);
        o4.w = f2bf(O[ct][3] * inv);
        *(short4*)&Z[(b * S_ + s) * (H_ * A_) + h * A_ + ct * 16 + quad * 4] = o4;
    }
}

// ---------------- kernel 4: output projection GEMM [4096 x 1024 x 1024] (R2/R8 reg-staged) -
__global__ __launch_bounds__(256) void proj_gemm(
    const short* __restrict__ Zb, const short* __restrict__ Wot,
    const float* __restrict__ bo, float* __restrict__ out) {
    const int mt = blockIdx.x, nt = blockIdx.y;
    const int m0 = mt * 128, n0 = nt * 64;
    __shared__ short Xl[2][128 * 40], Wl[2][64 * 40];
    const int tid = threadIdx.x, wv = tid >> 6, lane = tid & 63, quad = lane >> 4, l16 = lane & 15;
    const int grow = tid >> 1, gk = (tid & 1) * 16;
    const bool doW = (tid < 128);          // W tile 64x32 = 2048 shorts = 128 thr x 16
    f32x4 acc[4][2] = {};
    bf16x8 xr0, xr1, wr0, wr1;
    {
        const short* xs = &Zb[(m0 + grow) * D_ + gk];
        xr0 = *(const bf16x8*)xs; xr1 = *(const bf16x8*)(xs + 8);
        if (doW) {
            const short* wsp = &Wot[(n0 + grow) * D_ + gk];
            wr0 = *(const bf16x8*)wsp; wr1 = *(const bf16x8*)(wsp + 8);
        }
    }
    const int rm = (wv & 1) * 64, cn = (wv >> 1) * 32;
    for (int i = 0; i < 32; i++) {
        const int bu = i & 1;
        *(bf16x8*)&Xl[bu][grow * 40 + gk]     = xr0;
        *(bf16x8*)&Xl[bu][grow * 40 + gk + 8] = xr1;
        if (doW) {
            *(bf16x8*)&Wl[bu][grow * 40 + gk]     = wr0;
            *(bf16x8*)&Wl[bu][grow * 40 + gk + 8] = wr1;
        }
        __syncthreads();
        if (i < 31) {
            const int k0 = (i + 1) * 32;
            const short* xs = &Zb[(m0 + grow) * D_ + k0 + gk];
            xr0 = *(const bf16x8*)xs; xr1 = *(const bf16x8*)(xs + 8);
            if (doW) {
                const short* wsp = &Wot[(n0 + grow) * D_ + k0 + gk];
                wr0 = *(const bf16x8*)wsp; wr1 = *(const bf16x8*)(wsp + 8);
            }
        }
        bf16x8 af[4];
        #pragma unroll
        for (int rt = 0; rt < 4; rt++)
            af[rt] = *(bf16x8*)&Xl[bu][(rm + rt * 16 + l16) * 40 + quad * 8];
        #pragma unroll
        for (int ct = 0; ct < 2; ct++) {
            bf16x8 bf = *(bf16x8*)&Wl[bu][(cn + ct * 16 + l16) * 40 + quad * 8];
            #pragma unroll
            for (int rt = 0; rt < 4; rt++)
                acc[rt][ct] = __builtin_amdgcn_mfma_f32_16x16x32_bf16(af[rt], bf, acc[rt][ct], 0, 0, 0);
        }
    }
    #pragma unroll
    for (int ct = 0; ct < 2; ct++) {
        const int n = n0 + cn + ct * 16 + l16;
        const float bi = bo[n];
        #pragma unroll
        for (int rt = 0; rt < 4; rt++)
            #pragma unroll
            for (int r = 0; r < 4; r++) {
                const int row = m0 + rm + rt * 16 + quad * 4 + r;
                out[row * D_ + n] = acc[rt][ct][r] + bi;
            }
    }
}

extern "C" void kernel_launch(void* const* d_in, const int* in_sizes, int n_in,
                              void* d_out, int out_size, void* d_ws, size_t ws_size,
                              hipStream_t stream) {
    const float* residual = (const float*)d_in[0];
    const float* Wq = (const float*)d_in[1];
    const float* Wk = (const float*)d_in[2];
    const float* Wv = (const float*)d_in[3];
    const float* Wo = (const float*)d_in[4];
    const float* bq = (const float*)d_in[5];
    const float* bk = (const float*)d_in[6];
    const float* bv = (const float*)d_in[7];
    const float* bo = (const float*)d_in[8];
    float* out = (float*)d_out;

    char* ws = (char*)d_ws;
    const size_t NE = (size_t)B_ * S_ * D_;           // 4,194,304
    short* Xbf = (short*)(ws);                        //  8 MB  [B*S, D] bf16
    short* Wt  = (short*)(ws +  8ull * 1024 * 1024);  //  6 MB  [3072, 1024] bf16 (qkv, transposed)
    short* Wot = (short*)(ws + 14ull * 1024 * 1024);  //  2 MB  [1024, 1024] bf16 (Wo, transposed)
    short* Qb  = (short*)(ws + 16ull * 1024 * 1024);  //  8 MB  [B,H,S,A]
    short* Kb  = (short*)(ws + 24ull * 1024 * 1024);  //  8 MB  [B,H,S,A]
    short* Vt  = (short*)(ws + 32ull * 1024 * 1024);  //  8 MB  [B,H,A,S]
    short* Zb  = (short*)(ws + 40ull * 1024 * 1024);  //  8 MB  [B,S,H*A]

    hipLaunchKernelGGL(cast_kernel, dim3((int)(NE / (256 * 8))), dim3(256), 0, stream,
                       residual, Xbf, (int)NE);
    hipLaunchKernelGGL(wtrans_kernel, dim3(16, 16, 4), dim3(256), 0, stream,
                       Wq, Wk, Wv, Wo, Wt, Wot);
    hipLaunchKernelGGL(qkv_gemm, dim3(32, 24), dim3(256), 0, stream,
                       Xbf, Wt, bq, bk, bv, Qb, Kb, Vt);
    hipLaunchKernelGGL(flash_kernel, dim3(16, H_, B_), dim3(512), 0, stream,
                       Qb, Kb, Vt, Zb);
    hipLaunchKernelGGL(proj_gemm, dim3(32, 16), dim3(256), 0, stream,
                       Zb, Wot, bo, out);
}

// Round 16
// 191.496 us; speedup vs baseline: 1.0933x; 1.0177x over previous
//
#include <hip/hip_runtime.h>
#include <hip/hip_bf16.h>

// Problem constants: B=2, S=2048, D=1024, H=16, A=64
#define B_ 2
#define S_ 2048
#define D_ 1024
#define H_ 16
#define A_ 64

typedef __attribute__((ext_vector_type(8))) short bf16x8;
typedef __attribute__((ext_vector_type(4))) float f32x4;
typedef __attribute__((ext_vector_type(4))) unsigned int u32x4;
typedef __attribute__((ext_vector_type(2))) unsigned int u32x2;

#define QSCALE 0.1803368801111204f   // 1/sqrt(64) * log2(e): softmax done in exp2 domain
#define SMAX 8.0f                    // static softmax shift (exp2 domain); see flash_kernel

__device__ inline short f2bf(float f) {
    union { float f; unsigned u; } x; x.f = f;
    unsigned r = x.u + 0x7fff + ((x.u >> 16) & 1);   // RNE
    return (short)(r >> 16);
}

// ---- gfx950 register-only cross-lane helpers (VALU; no LDS pipe) ----
__device__ inline unsigned cvt_pk_bf16(float lo, float hi) {
    unsigned r;
    asm("v_cvt_pk_bf16_f32 %0, %1, %2" : "=v"(r) : "v"(lo), "v"(hi));
    return r;
}
__device__ inline void pl32swap(unsigned &a, unsigned &b) {
    u32x2 r = __builtin_amdgcn_permlane32_swap(a, b, false, false);
    a = r[0]; b = r[1];
}
__device__ inline void pl16swap(unsigned &a, unsigned &b) {
    u32x2 r = __builtin_amdgcn_permlane16_swap(a, b, false, false);
    a = r[0]; b = r[1];
}
__device__ inline float cross_quad_sum(float x) {
    unsigned a = __builtin_bit_cast(unsigned, x), b = a;
    pl32swap(a, b);
    float y = __builtin_bit_cast(float, a) + __builtin_bit_cast(float, b);
    unsigned c = __builtin_bit_cast(unsigned, y), d = c;
    pl16swap(c, d);
    return __builtin_bit_cast(float, c) + __builtin_bit_cast(float, d);
}

// ---------------- kernel 1: fp32 -> bf16 cast of residual ----------------
__global__ __launch_bounds__(256) void cast_kernel(const float* __restrict__ x,
                                                   short* __restrict__ y, int n) {
    int i = (blockIdx.x * 256 + threadIdx.x) * 8;
    if (i < n) {
        float4 a = *(const float4*)(x + i);
        float4 b = *(const float4*)(x + i + 4);
        bf16x8 o;
        o[0]=f2bf(a.x); o[1]=f2bf(a.y); o[2]=f2bf(a.z); o[3]=f2bf(a.w);
        o[4]=f2bf(b.x); o[5]=f2bf(b.y); o[6]=f2bf(b.z); o[7]=f2bf(b.w);
        *(bf16x8*)(y + i) = o;
    }
}

// ---------------- kernel 1b: transpose+cast weights to bf16 [n][k] ----------------
__global__ __launch_bounds__(256) void wtrans_kernel(
    const float* __restrict__ Wq, const float* __restrict__ Wk,
    const float* __restrict__ Wv, const float* __restrict__ Wo,
    short* __restrict__ Wt, short* __restrict__ Wot) {
    const int kt = blockIdx.x, yy = blockIdx.y, z = blockIdx.z;
    __shared__ short T[64 * 72];
    const int tid = threadIdx.x;
    const int r = tid >> 2, c0 = (tid & 3) * 16;
    const float* src;
    if (z < 3) {
        const float* W = z == 0 ? Wq : (z == 1 ? Wk : Wv);
        src = &W[yy * (D_ * A_) + (kt * 64 + r) * A_ + c0];
    } else {
        src = &Wo[(kt * 64 + r) * D_ + yy * 64 + c0];
    }
    #pragma unroll
    for (int q = 0; q < 4; q++) {
        float4 f = *(const float4*)(src + q * 4);
        T[r * 72 + c0 + q * 4 + 0] = f2bf(f.x);
        T[r * 72 + c0 + q * 4 + 1] = f2bf(f.y);
        T[r * 72 + c0 + q * 4 + 2] = f2bf(f.z);
        T[r * 72 + c0 + q * 4 + 3] = f2bf(f.w);
    }
    __syncthreads();
    const int a = tid >> 2, kc = (tid & 3) * 16;
    bf16x8 o0, o1;
    #pragma unroll
    for (int j = 0; j < 8; j++) {
        o0[j] = T[(kc + j) * 72 + a];
        o1[j] = T[(kc + 8 + j) * 72 + a];
    }
    const int n_base = (z < 3) ? z * 1024 + yy * 64 : yy * 64;
    short* dst = (z < 3) ? &Wt[(n_base + a) * D_ + kt * 64 + kc]
                         : &Wot[(n_base + a) * D_ + kt * 64 + kc];
    *(bf16x8*)dst = o0;
    *(bf16x8*)(dst + 8) = o1;
}

// ---------------- kernel 2: QKV as one GEMM [4096 x 3072 x 1024] (R2/R8 reg-staged) -------
__global__ __launch_bounds__(256) void qkv_gemm(
    const short* __restrict__ X, const short* __restrict__ Wt,
    const float* __restrict__ bq, const float* __restrict__ bk, const float* __restrict__ bv,
    short* __restrict__ Qb, short* __restrict__ Kb, short* __restrict__ Vt) {
    const int mt = blockIdx.x, nt = blockIdx.y;
    const int m0 = mt * 128, n0 = nt * 128;
    const int sel = n0 >> 10;
    __shared__ short Xl[2][128 * 40], Wl[2][128 * 40];
    const int tid = threadIdx.x, wv = tid >> 6, lane = tid & 63, quad = lane >> 4, l16 = lane & 15;
    const int grow = tid >> 1, gk = (tid & 1) * 16;
    f32x4 acc[4][4] = {};
    bf16x8 xr0, xr1, wr0, wr1;
    {
        const short* xs = &X[(m0 + grow) * D_ + gk];
        xr0 = *(const bf16x8*)xs; xr1 = *(const bf16x8*)(xs + 8);
        const short* wsp = &Wt[(n0 + grow) * D_ + gk];
        wr0 = *(const bf16x8*)wsp; wr1 = *(const bf16x8*)(wsp + 8);
    }
    const int rm = (wv & 1) * 64, cn = (wv >> 1) * 64;
    for (int i = 0; i < 32; i++) {
        const int bu = i & 1;
        *(bf16x8*)&Xl[bu][grow * 40 + gk]     = xr0;
        *(bf16x8*)&Xl[bu][grow * 40 + gk + 8] = xr1;
        *(bf16x8*)&Wl[bu][grow * 40 + gk]     = wr0;
        *(bf16x8*)&Wl[bu][grow * 40 + gk + 8] = wr1;
        __syncthreads();
        if (i < 31) {
            const int k0 = (i + 1) * 32;
            const short* xs = &X[(m0 + grow) * D_ + k0 + gk];
            xr0 = *(const bf16x8*)xs; xr1 = *(const bf16x8*)(xs + 8);
            const short* wsp = &Wt[(n0 + grow) * D_ + k0 + gk];
            wr0 = *(const bf16x8*)wsp; wr1 = *(const bf16x8*)(wsp + 8);
        }
        bf16x8 af[4];
        #pragma unroll
        for (int rt = 0; rt < 4; rt++)
            af[rt] = *(bf16x8*)&Xl[bu][(rm + rt * 16 + l16) * 40 + quad * 8];
        #pragma unroll
        for (int ct = 0; ct < 4; ct++) {
            bf16x8 bf = *(bf16x8*)&Wl[bu][(cn + ct * 16 + l16) * 40 + quad * 8];
            #pragma unroll
            for (int rt = 0; rt < 4; rt++)
                acc[rt][ct] = __builtin_amdgcn_mfma_f32_16x16x32_bf16(af[rt], bf, acc[rt][ct], 0, 0, 0);
        }
    }
    const int b = m0 >> 11;
    const float* bias = sel == 0 ? bq : (sel == 1 ? bk : bv);
    if (sel < 2) {
        short* dst = sel == 0 ? Qb : Kb;
        const float scale = sel == 0 ? QSCALE : 1.0f;
        #pragma unroll
        for (int ct = 0; ct < 4; ct++) {
            const int n = n0 + cn + ct * 16 + l16;
            const int h = (n >> 6) & 15, a = n & 63;
            const float bi = bias[n & 1023];
            #pragma unroll
            for (int rt = 0; rt < 4; rt++)
                #pragma unroll
                for (int r = 0; r < 4; r++) {
                    const int row = m0 + rm + rt * 16 + quad * 4 + r;
                    const int s = row & (S_ - 1);
                    dst[(((b * H_) + h) * S_ + s) * A_ + a] = f2bf((acc[rt][ct][r] + bi) * scale);
                }
        }
    } else {
        #pragma unroll
        for (int ct = 0; ct < 4; ct++) {
            const int n = n0 + cn + ct * 16 + l16;
            const int h = (n >> 6) & 15, a = n & 63;
            const float bi = bias[n & 1023];
            #pragma unroll
            for (int rt = 0; rt < 4; rt++) {
                short4 pk;
                pk.x = f2bf(acc[rt][ct][0] + bi);
                pk.y = f2bf(acc[rt][ct][1] + bi);
                pk.z = f2bf(acc[rt][ct][2] + bi);
                pk.w = f2bf(acc[rt][ct][3] + bi);
                const int row = m0 + rm + rt * 16 + quad * 4;
                const int s = row & (S_ - 1);
                *(short4*)&Vt[(((b * H_) + h) * A_ + a) * S_ + s] = pk;
            }
        }
    }
}

// ---------------- kernel 3: flash attention — KVBLK=128, static-max softmax (R16) ---------
// R16 change vs R15 (single lever): stage TWO 64-k tiles per round (KVBLK=128), compute
// them as sequential sub-tiles (LDS offset sub*4096; fragment decode within each half
// identical to R15). Rounds per block: 2x+2 -> x+1; per-CU barrier count 34 -> 17 with
// the same MFMA/VALU work. Double-buffer hazard algebra unchanged (write buf[r&1] ->
// barrier -> read buf[r&1]; one barrier separates cross-round clobbers). LDS 32->64KB,
// still 2 blocks/CU. Per-sub causal guard: ksub = 2r+sub vs myqt.
__global__ __launch_bounds__(512, 4) void flash_kernel(
    const short* __restrict__ Qb, const short* __restrict__ Kb,
    const short* __restrict__ Vt, short* __restrict__ Z) {
    const int xx = blockIdx.x, h = blockIdx.y, b = blockIdx.z;
    const int x = (((h >> 3) ^ b) & 1) ? (15 - xx) : xx;
    const int bh = b * H_ + h;
    const int qa = 2 * x, qb = 2 * x + 1;   // adjacent q-tiles; qmax = qb
    __shared__ short Kl[2][8192], Vl[2][8192];
    const int tid = threadIdx.x, wv = tid >> 6, lane = tid & 63, quad = lane >> 4, l16 = lane & 15;
    const int wg = wv & 3;
    const int myqt = (wv < 4) ? qb : qa;
    const int qpos = wg * 16 + l16;

    const int L = tid;
    const int srow = (L >> 7) * 16 + (L & 15);
    const int scol = ((L >> 6) & 1) * 32 + ((L >> 4) & 3) * 8;

    const short* qptr = &Qb[(bh * S_ + myqt * 64 + wg * 16 + l16) * A_ + quad * 8];
    bf16x8 qf[2] = { *(const bf16x8*)qptr, *(const bf16x8*)(qptr + 32) };

    f32x4 O[4] = {};
    float l_i = 0.f;                       // in-lane partial row-sum (cross-quad at end)

    const short* kgp = &Kb[(bh * S_ + srow) * A_ + scol];
    const short* vgp = &Vt[(bh * A_ + srow) * S_ + scol];
    bf16x8 k0 = *(const bf16x8*)(kgp);
    bf16x8 k1 = *(const bf16x8*)(kgp + 64 * A_);
    bf16x8 v0 = *(const bf16x8*)(vgp);
    bf16x8 v1 = *(const bf16x8*)(vgp + 64);

    const int R = x + 1;                   // 128-wide k rounds
    for (int rnd = 0; rnd < R; rnd++) {
        const int bu = rnd & 1;
        *(bf16x8*)&Kl[bu][L * 8]        = k0;
        *(bf16x8*)&Kl[bu][4096 + L * 8] = k1;
        *(bf16x8*)&Vl[bu][L * 8]        = v0;
        *(bf16x8*)&Vl[bu][4096 + L * 8] = v1;
        __syncthreads();
        if (rnd < R - 1) {
            const int o = (rnd + 1) * 128;
            k0 = *(const bf16x8*)(kgp + o * A_);
            k1 = *(const bf16x8*)(kgp + (o + 64) * A_);
            v0 = *(const bf16x8*)(vgp + o);
            v1 = *(const bf16x8*)(vgp + o + 64);
        }
        #pragma unroll
        for (int sub = 0; sub < 2; sub++) {
            const int ksub = 2 * rnd + sub;
            if (ksub <= myqt) {
                const int sb = sub * 4096;
                f32x4 sacc[4] = {};
                #pragma unroll
                for (int kk = 0; kk < 2; kk++)
                    #pragma unroll
                    for (int ct = 0; ct < 4; ct++) {
                        bf16x8 kf = *(bf16x8*)&Kl[bu][sb + ((ct * 2 + kk) * 64 + lane) * 8];
                        sacc[ct] = __builtin_amdgcn_mfma_f32_16x16x32_bf16(kf, qf[kk], sacc[ct], 0, 0, 0);
                    }
                if (ksub == myqt) {
                    #pragma unroll
                    for (int ct = 0; ct < 4; ct++)
                        #pragma unroll
                        for (int r = 0; r < 4; r++)
                            if (ct * 16 + quad * 4 + r > qpos) sacc[ct][r] = -1e30f;
                }
                // static-shift softmax numerator: p = exp2(s - SMAX); masked -> 0
                #pragma unroll
                for (int ct = 0; ct < 4; ct++)
                    #pragma unroll
                    for (int r = 0; r < 4; r++)
                        sacc[ct][r] = exp2f(sacc[ct][r] - SMAX);
                f32x4 ps;
                #pragma unroll
                for (int r = 0; r < 4; r++)
                    ps[r] = (sacc[0][r] + sacc[1][r]) + (sacc[2][r] + sacc[3][r]);
                l_i += (ps[0] + ps[1]) + (ps[2] + ps[3]);
                #pragma unroll
                for (int kk = 0; kk < 2; kk++) {
                    unsigned A0 = cvt_pk_bf16(sacc[2 * kk][0], sacc[2 * kk][1]);
                    unsigned A1 = cvt_pk_bf16(sacc[2 * kk][2], sacc[2 * kk][3]);
                    unsigned B0 = cvt_pk_bf16(sacc[2 * kk + 1][0], sacc[2 * kk + 1][1]);
                    unsigned B1 = cvt_pk_bf16(sacc[2 * kk + 1][2], sacc[2 * kk + 1][3]);
                    pl32swap(A0, B0);
                    pl16swap(A0, B0);
                    pl32swap(A1, B1);
                    pl16swap(A1, B1);
                    u32x4 wu; wu[0] = A0; wu[1] = A1; wu[2] = B0; wu[3] = B1;
                    bf16x8 pb = __builtin_bit_cast(bf16x8, wu);
                    #pragma unroll
                    for (int ct = 0; ct < 4; ct++) {
                        bf16x8 vf = *(bf16x8*)&Vl[bu][sb + ((ct * 2 + kk) * 64 + lane) * 8];
                        O[ct] = __builtin_amdgcn_mfma_f32_16x16x32_bf16(vf, pb, O[ct], 0, 0, 0);
                    }
                }
            }
        }
    }
    const float inv = 1.0f / cross_quad_sum(l_i);
    const int s = myqt * 64 + wg * 16 + l16;
    #pragma unroll
    for (int ct = 0; ct < 4; ct++) {
        short4 o4;
        o4.x = f2bf(O[ct][0] * inv);
        o4.y = f2bf(O[ct][1] * inv);
        o4.z = f2bf(O[ct][2] * inv);
        o4.w = f2bf(O[ct][3] * inv);
        *(short4*)&Z[(b * S_ + s) * (H_ * A_) + h * A_ + ct * 16 + quad * 4] = o4;
    }
}

// ---------------- kernel 4: output projection GEMM [4096 x 1024 x 1024] (R2/R8 reg-staged) -
__global__ __launch_bounds__(256) void proj_gemm(
    const short* __restrict__ Zb, const short* __restrict__ Wot,
    const float* __restrict__ bo, float* __restrict__ out) {
    const int mt = blockIdx.x, nt = blockIdx.y;
    const int m0 = mt * 128, n0 = nt * 64;
    __shared__ short Xl[2][128 * 40], Wl[2][64 * 40];
    const int tid = threadIdx.x, wv = tid >> 6, lane = tid & 63, quad = lane >> 4, l16 = lane & 15;
    const int grow = tid >> 1, gk = (tid & 1) * 16;
    const bool doW = (tid < 128);          // W tile 64x32 = 2048 shorts = 128 thr x 16
    f32x4 acc[4][2] = {};
    bf16x8 xr0, xr1, wr0, wr1;
    {
        const short* xs = &Zb[(m0 + grow) * D_ + gk];
        xr0 = *(const bf16x8*)xs; xr1 = *(const bf16x8*)(xs + 8);
        if (doW) {
            const short* wsp = &Wot[(n0 + grow) * D_ + gk];
            wr0 = *(const bf16x8*)wsp; wr1 = *(const bf16x8*)(wsp + 8);
        }
    }
    const int rm = (wv & 1) * 64, cn = (wv >> 1) * 32;
    for (int i = 0; i < 32; i++) {
        const int bu = i & 1;
        *(bf16x8*)&Xl[bu][grow * 40 + gk]     = xr0;
        *(bf16x8*)&Xl[bu][grow * 40 + gk + 8] = xr1;
        if (doW) {
            *(bf16x8*)&Wl[bu][grow * 40 + gk]     = wr0;
            *(bf16x8*)&Wl[bu][grow * 40 + gk + 8] = wr1;
        }
        __syncthreads();
        if (i < 31) {
            const int k0 = (i + 1) * 32;
            const short* xs = &Zb[(m0 + grow) * D_ + k0 + gk];
            xr0 = *(const bf16x8*)xs; xr1 = *(const bf16x8*)(xs + 8);
            if (doW) {
                const short* wsp = &Wot[(n0 + grow) * D_ + k0 + gk];
                wr0 = *(const bf16x8*)wsp; wr1 = *(const bf16x8*)(wsp + 8);
            }
        }
        bf16x8 af[4];
        #pragma unroll
        for (int rt = 0; rt < 4; rt++)
            af[rt] = *(bf16x8*)&Xl[bu][(rm + rt * 16 + l16) * 40 + quad * 8];
        #pragma unroll
        for (int ct = 0; ct < 2; ct++) {
            bf16x8 bf = *(bf16x8*)&Wl[bu][(cn + ct * 16 + l16) * 40 + quad * 8];
            #pragma unroll
            for (int rt = 0; rt < 4; rt++)
                acc[rt][ct] = __builtin_amdgcn_mfma_f32_16x16x32_bf16(af[rt], bf, acc[rt][ct], 0, 0, 0);
        }
    }
    #pragma unroll
    for (int ct = 0; ct < 2; ct++) {
        const int n = n0 + cn + ct * 16 + l16;
        const float bi = bo[n];
        #pragma unroll
        for (int rt = 0; rt < 4; rt++)
            #pragma unroll
            for (int r = 0; r < 4; r++) {
                const int row = m0 + rm + rt * 16 + quad * 4 + r;
                out[row * D_ + n] = acc[rt][ct][r] + bi;
            }
    }
}

extern "C" void kernel_launch(void* const* d_in, const int* in_sizes, int n_in,
                              void* d_out, int out_size, void* d_ws, size_t ws_size,
                              hipStream_t stream) {
    const float* residual = (const float*)d_in[0];
    const float* Wq = (const float*)d_in[1];
    const float* Wk = (const float*)d_in[2];
    const float* Wv = (const float*)d_in[3];
    const float* Wo = (const float*)d_in[4];
    const float* bq = (const float*)d_in[5];
    const float* bk = (const float*)d_in[6];
    const float* bv = (const float*)d_in[7];
    const float* bo = (const float*)d_in[8];
    float* out = (float*)d_out;

    char* ws = (char*)d_ws;
    const size_t NE = (size_t)B_ * S_ * D_;           // 4,194,304
    short* Xbf = (short*)(ws);                        //  8 MB  [B*S, D] bf16
    short* Wt  = (short*)(ws +  8ull * 1024 * 1024);  //  6 MB  [3072, 1024] bf16 (qkv, transposed)
    short* Wot = (short*)(ws + 14ull * 1024 * 1024);  //  2 MB  [1024, 1024] bf16 (Wo, transposed)
    short* Qb  = (short*)(ws + 16ull * 1024 * 1024);  //  8 MB  [B,H,S,A]
    short* Kb  = (short*)(ws + 24ull * 1024 * 1024);  //  8 MB  [B,H,S,A]
    short* Vt  = (short*)(ws + 32ull * 1024 * 1024);  //  8 MB  [B,H,A,S]
    short* Zb  = (short*)(ws + 40ull * 1024 * 1024);  //  8 MB  [B,S,H*A]

    hipLaunchKernelGGL(cast_kernel, dim3((int)(NE / (256 * 8))), dim3(256), 0, stream,
                       residual, Xbf, (int)NE);
    hipLaunchKernelGGL(wtrans_kernel, dim3(16, 16, 4), dim3(256), 0, stream,
                       Wq, Wk, Wv, Wo, Wt, Wot);
    hipLaunchKernelGGL(qkv_gemm, dim3(32, 24), dim3(256), 0, stream,
                       Xbf, Wt, bq, bk, bv, Qb, Kb, Vt);
    hipLaunchKernelGGL(flash_kernel, dim3(16, H_, B_), dim3(512), 0, stream,
                       Qb, Kb, Vt, Zb);
    hipLaunchKernelGGL(proj_gemm, dim3(32, 16), dim3(256), 0, stream,
                       Zb, Wot, bo, out);
}